// Round 1
// baseline (1499.363 us; speedup 1.0000x reference)
//
#include <hip/hip_runtime.h>
#include <math.h>

// Problem constants (from reference)
constexpr int BATCH = 1024;
constexpr int C = 1000;            // NUM_CLASSES
constexpr int NUM_EXAMP = 200000;
constexpr float BETA = 0.7f;
constexpr float ONE_MINUS_BETA = 1.0f - 0.7f;
constexpr float LAMBDA1 = 3.0f;
constexpr float CLIP_EPS = 1e-4f;

// One block per batch row. 256 threads, each handles <=4 of the 1000 columns.
__global__ __launch_bounds__(256) void elr_row_kernel(
    const float* __restrict__ output,     // [BATCH, C]
    const float* __restrict__ target,     // [NUM_EXAMP, C] (pristine input)
    const int*   __restrict__ label,      // [BATCH]
    const int*   __restrict__ index,      // [1]
    float* __restrict__ new_target,       // d_out + 1, [NUM_EXAMP, C]
    float* __restrict__ partial)          // [BATCH] loss partials (ws)
{
    const int row = blockIdx.x;
    const int tid = threadIdx.x;
    const int start = index[0] * BATCH;

    const float* x = output + (size_t)row * C;
    __shared__ float red[256];

    // ---- load logits (registers), row max ----
    float v[4];
    float tmax = -INFINITY;
#pragma unroll
    for (int k = 0; k < 4; ++k) {
        int j = tid + k * 256;
        v[k] = (j < C) ? x[j] : -INFINITY;
        tmax = fmaxf(tmax, v[k]);
    }
    red[tid] = tmax;
    __syncthreads();
    for (int s = 128; s > 0; s >>= 1) {
        if (tid < s) red[tid] = fmaxf(red[tid], red[tid + s]);
        __syncthreads();
    }
    const float m = red[0];
    __syncthreads();

    // ---- exp + sum ----
    float e[4];
    float tsum = 0.f;
#pragma unroll
    for (int k = 0; k < 4; ++k) {
        int j = tid + k * 256;
        e[k] = (j < C) ? expf(v[k] - m) : 0.f;
        tsum += e[k];
    }
    red[tid] = tsum;
    __syncthreads();
    for (int s = 128; s > 0; s >>= 1) {
        if (tid < s) red[tid] += red[tid + s];
        __syncthreads();
    }
    const float ssum = red[0];
    __syncthreads();

    // ---- y_pred = clamp(softmax), sum for renorm ----
    const float inv_s = 1.0f / ssum;
    float yp[4];
    float tclip = 0.f;
#pragma unroll
    for (int k = 0; k < 4; ++k) {
        int j = tid + k * 256;
        float p = e[k] * inv_s;
        p = fminf(fmaxf(p, CLIP_EPS), 1.0f - CLIP_EPS);
        yp[k] = (j < C) ? p : 0.f;
        tclip += yp[k];
    }
    red[tid] = tclip;
    __syncthreads();
    for (int s = 128; s > 0; s >>= 1) {
        if (tid < s) red[tid] += red[tid + s];
        __syncthreads();
    }
    const float inv_t = 1.0f / red[0];
    __syncthreads();

    // ---- EMA update of the slice rows + dot(new_row, y_pred) ----
    const size_t grow = (size_t)(start + row) * C;
    float tdot = 0.f;
#pragma unroll
    for (int k = 0; k < 4; ++k) {
        int j = tid + k * 256;
        if (j < C) {
            float yn = yp[k] * inv_t;                       // renormalized detached pred
            float nr = BETA * target[grow + j] + ONE_MINUS_BETA * yn;
            new_target[grow + j] = nr;                      // overwrites bulk-copied row
            tdot += nr * yp[k];
        }
    }
    red[tid] = tdot;
    __syncthreads();
    for (int s = 128; s > 0; s >>= 1) {
        if (tid < s) red[tid] += red[tid + s];
        __syncthreads();
    }

    if (tid == 0) {
        float dot = red[0];
        int lab = label[row];
        float logp = x[lab] - m - logf(ssum);               // log_softmax at label
        float ce = -logp;
        float elr = log1pf(-dot);                           // log(1 - dot), dot << 1
        partial[row] = (ce + LAMBDA1 * elr) * (1.0f / (float)BATCH);
    }
}

// Deterministic final reduction of BATCH partials -> d_out[0]
__global__ __launch_bounds__(256) void elr_reduce_kernel(
    const float* __restrict__ partial, float* __restrict__ out)
{
    __shared__ float red[256];
    const int tid = threadIdx.x;
    float s = 0.f;
    for (int i = tid; i < BATCH; i += 256) s += partial[i];
    red[tid] = s;
    __syncthreads();
    for (int st = 128; st > 0; st >>= 1) {
        if (tid < st) red[tid] += red[tid + st];
        __syncthreads();
    }
    if (tid == 0) out[0] = red[0];
}

extern "C" void kernel_launch(void* const* d_in, const int* in_sizes, int n_in,
                              void* d_out, int out_size, void* d_ws, size_t ws_size,
                              hipStream_t stream) {
    const float* output = (const float*)d_in[0];
    const float* target = (const float*)d_in[1];
    const int*   label  = (const int*)d_in[2];
    const int*   index  = (const int*)d_in[3];

    float* out        = (float*)d_out;
    float* new_target = out + 1;          // outputs concatenated: [loss, new_target...]
    float* partial    = (float*)d_ws;     // BATCH floats

    // 1) Bulk copy target -> new_target (800 MB). Stream-ordered; slice rows get
    //    overwritten by the row kernel afterwards.
    hipMemcpyAsync(new_target, target,
                   (size_t)NUM_EXAMP * (size_t)C * sizeof(float),
                   hipMemcpyDeviceToDevice, stream);

    // 2) Per-row softmax/clamp/renorm/EMA + loss partials.
    elr_row_kernel<<<BATCH, 256, 0, stream>>>(output, target, label, index,
                                              new_target, partial);

    // 3) Final loss scalar.
    elr_reduce_kernel<<<1, 256, 0, stream>>>(partial, out);
}